// Round 15
// baseline (350.897 us; speedup 1.0000x reference)
//
#include <hip/hip_runtime.h>
#include <hip/hip_bf16.h>

// GCN on MI355X. Pipeline (13 dispatches):
//   k_bhist   - per-block bucket histogram -> cnt_all (no atomics)
//               + merged wprep (W->bf16 Wt) + pool/cnt zeroing
//   k_colscan - one wave per bucket shfl-scan of cnt_all columns
//   k_bscan   - exclusive scan over buckets -> bbase
//   k_bucket  - placement only (lbase = bbase + cnt_all precomputed)
//   k_sort    - per-bucket LDS counting sort -> CSR + rowptr/rowend/dinv
//   k_wfgemm1 - FUSED: wfill blocks (csr_w[e]=dinv[csr_s[e]]) + GEMM-1 blocks
//   k_agg x3  - FOUR nodes per wave (lane quarter q stages node q's edges,
//               16 slots each); 4 independent gather chains, <=16 gathers
//               in flight. Extends R12's proven 2-node pattern.
//   k_gemm x2, k_pool (run-length reduce), k_final
// RULE (R3, R13): never emit >~100 atomics per address; pre-reduce first.
// k_agg is bound by random 64B-line request rate (~2.5M lines / ~77G/s).
// All ws-derived loop bounds are clamped (rocprof counter-replay safety).

#define BSHIFT 7
#define BNODES (1 << BSHIFT)
#define EPB    8192
#define MAXDEG 8192
#define MAXBUCKET 32768

typedef __attribute__((ext_vector_type(8))) short bf16x8;
typedef __attribute__((ext_vector_type(4))) float f32x4;

__device__ __forceinline__ void atomAddF(float* p, float v) {
#if defined(__gfx90a__) || defined(__gfx940__) || defined(__gfx941__) || defined(__gfx942__) || defined(__gfx950__)
    unsafeAtomicAdd(p, v);
#else
    atomicAdd(p, v);
#endif
}

__device__ __forceinline__ unsigned short f2bf(float x) {   // RNE fp32->bf16
    unsigned u = __float_as_uint(x);
    u += 0x7FFFu + ((u >> 16) & 1u);
    return (unsigned short)(u >> 16);
}
__device__ __forceinline__ float bf2f(unsigned short b) {
    return __uint_as_float((unsigned)b << 16);
}

// ---------------- histogram + weight prep + pool zeroing ----------------
__global__ __launch_bounds__(256)
void k_bhist(const int* __restrict__ dst, int* __restrict__ cnt_all,
             int nE, int nBuckets, int binBlocks,
             const float* __restrict__ W1, const float* __restrict__ W2,
             const float* __restrict__ W3, unsigned short* __restrict__ Wt,
             float* __restrict__ pool, int poolN) {
    if (blockIdx.x >= binBlocks) {
        int li = blockIdx.x - binBlocks;          // 0..2 wprep, 3 = pool zero
        if (li < 3) {
            const float* W = (li == 0) ? W1 : ((li == 1) ? W2 : W3);
            unsigned short* o = Wt + li * 4096;
            for (int idx = threadIdx.x; idx < 4096; idx += 256) {
                int h = idx >> 6, k = idx & 63;
                o[idx] = f2bf(W[k * 64 + h]);
            }
        } else {
            for (int i = threadIdx.x; i < poolN; i += 256) pool[i] = 0.f;
        }
        return;
    }
    __shared__ int cnt[1024];
    const int t = threadIdx.x;
    const int blk = blockIdx.x * EPB;
    for (int b = t; b < nBuckets; b += 256) cnt[b] = 0;
    __syncthreads();
#pragma unroll 4
    for (int i = 0; i < EPB / 256; i++) {
        int e = blk + i * 256 + t;
        if (e < nE) atomicAdd(&cnt[dst[e] >> BSHIFT], 1);
    }
    __syncthreads();
    for (int b = t; b < nBuckets; b += 256)
        cnt_all[(size_t)blockIdx.x * nBuckets + b] = cnt[b];
}

// ---------------- column scan: one wave per bucket ----------------
__global__ __launch_bounds__(256)
void k_colscan(int* __restrict__ cnt_all, int* __restrict__ bcnt,
               int nBlocks, int nBuckets) {
    const int lane = threadIdx.x & 63;
    const int b = blockIdx.x * 4 + (threadIdx.x >> 6);
    if (b >= nBuckets) return;
    int running = 0;
    for (int c = 0; c < nBlocks; c += 64) {
        int blk = c + lane;
        int v = (blk < nBlocks) ? cnt_all[(size_t)blk * nBuckets + b] : 0;
        int incl = v;
#pragma unroll
        for (int off = 1; off < 64; off <<= 1) {
            int tv = __shfl_up(incl, off);
            if (lane >= off) incl += tv;
        }
        if (blk < nBlocks) cnt_all[(size_t)blk * nBuckets + b] = running + (incl - v);
        running += __shfl(incl, 63);
    }
    if (lane == 0) bcnt[b] = running;
}

// ---------------- bucket scan (nb <= 1024) -> bbase ----------------
__global__ void k_bscan(const int* __restrict__ bcnt, int* __restrict__ bbase,
                        int nb, int nE) {
    __shared__ int s[256];
    const int t = threadIdx.x;
    const int base = t * 4;
    int v0 = (base + 0 < nb) ? bcnt[base + 0] : 0;
    int v1 = (base + 1 < nb) ? bcnt[base + 1] : 0;
    int v2 = (base + 2 < nb) ? bcnt[base + 2] : 0;
    int v3 = (base + 3 < nb) ? bcnt[base + 3] : 0;
    int tsum = v0 + v1 + v2 + v3;
    s[t] = tsum;
    __syncthreads();
    for (int off = 1; off < 256; off <<= 1) {
        int val = 0;
        if (t >= off) val = s[t - off];
        __syncthreads();
        if (t >= off) s[t] += val;
        __syncthreads();
    }
    int excl = s[t] - tsum;
    if (base + 0 < nb) bbase[base + 0] = excl;
    if (base + 1 < nb) bbase[base + 1] = excl + v0;
    if (base + 2 < nb) bbase[base + 2] = excl + v0 + v1;
    if (base + 3 < nb) bbase[base + 3] = excl + v0 + v1 + v2;
    if (t == 0) bbase[nb] = nE;
}

// ---------------- bucket placement ----------------
__global__ __launch_bounds__(256)
void k_bucket(const int* __restrict__ src, const int* __restrict__ dst,
              const int* __restrict__ bbase, const int* __restrict__ cnt_all,
              int* __restrict__ staging, int nE, int nBuckets) {
    __shared__ int cnt[1024];
    __shared__ int lbase[1024];
    const int t = threadIdx.x;
    const int blk = blockIdx.x * EPB;

    for (int b = t; b < nBuckets; b += 256) {
        lbase[b] = bbase[b] + cnt_all[(size_t)blockIdx.x * nBuckets + b];
        cnt[b] = 0;
    }
    __syncthreads();
#pragma unroll 4
    for (int i = 0; i < EPB / 256; i++) {
        int e = blk + i * 256 + t;
        if (e < nE) {
            int s0 = src[e], d0 = dst[e];
            int b = d0 >> BSHIFT;
            int off = atomicAdd(&cnt[b], 1);
            int pos = lbase[b] + off;
            if ((unsigned)pos < (unsigned)nE)
                staging[pos] = (s0 << BSHIFT) | (d0 & (BNODES - 1));
        }
    }
}

// ---------------- per-bucket counting sort -> CSR + rowptr/rowend/dinv ----------
__global__ __launch_bounds__(256)
void k_sort(const int* __restrict__ staging, const int* __restrict__ bbase,
            int* __restrict__ csr_s, int* __restrict__ rowptr,
            int* __restrict__ rowend, float* __restrict__ dinv,
            int n, int nE) {
    __shared__ int c[BNODES];
    __shared__ int sc[BNODES];
    __shared__ int cur[BNODES];
    const int t = threadIdx.x;
    const int b = blockIdx.x;
    const int node0 = b << BSHIFT;

    int seg0 = bbase[b];
    int seg1 = bbase[b + 1];
    seg0 = max(0, min(seg0, nE));
    seg1 = max(seg0, min(seg1, nE));
    seg1 = min(seg1, seg0 + MAXBUCKET);

    if (t < BNODES) c[t] = 0;
    __syncthreads();
    for (int e = seg0 + t; e < seg1; e += 256)
        atomicAdd(&c[staging[e] & (BNODES - 1)], 1);
    __syncthreads();
    if (t < BNODES) sc[t] = c[t];
    __syncthreads();
    for (int off = 1; off < BNODES; off <<= 1) {
        int v = 0;
        if (t >= off && t < BNODES) v = sc[t - off];
        __syncthreads();
        if (t >= off && t < BNODES) sc[t] += v;
        __syncthreads();
    }
    if (t < BNODES) {
        int excl = sc[t] - c[t];
        cur[t] = excl;
        int node = node0 + t;
        if (node < n) {
            rowptr[node] = seg0 + excl;
            rowend[node] = seg0 + excl + c[t];
            dinv[node]   = rsqrtf((float)c[t] + 1.0f);
        }
    }
    __syncthreads();
    for (int e = seg0 + t; e < seg1; e += 256) {
        int p = staging[e];
        int l = p & (BNODES - 1);
        int pos = seg0 + atomicAdd(&cur[l], 1);
        if ((unsigned)pos < (unsigned)nE)
            csr_s[pos] = ((unsigned)p) >> BSHIFT;
    }
}

// ---------------- MFMA GEMM body (shared by k_gemm and k_wfgemm1) -------------
template<bool RELU, typename AT>
__device__ __forceinline__
void gemm_body(int bid, const AT* __restrict__ in,
               const unsigned short* __restrict__ Wt,
               const float* __restrict__ bias,
               unsigned short* __restrict__ out, int n) {
    const int lane = threadIdx.x & 63;
    const int wid  = threadIdx.x >> 6;
    const int col  = lane & 15;
    const int quad = lane >> 4;
    const int node0w = bid * 64 + wid * 16;
    const int nodeA  = node0w + col;
    const bool validA = nodeA < n;

    f32x4 zero4 = {0.f, 0.f, 0.f, 0.f};
    f32x4 acc0 = zero4, acc1 = zero4, acc2 = zero4, acc3 = zero4;

#pragma unroll
    for (int ks = 0; ks < 64; ks += 32) {
        const int kb = ks + quad * 8;
        float a[8];
        if constexpr (sizeof(AT) == 4) {
            float4 a0 = make_float4(0.f, 0.f, 0.f, 0.f);
            float4 a1 = make_float4(0.f, 0.f, 0.f, 0.f);
            if (validA) {
                a0 = *(const float4*)((const float*)in + (size_t)nodeA * 64 + kb);
                a1 = *(const float4*)((const float*)in + (size_t)nodeA * 64 + kb + 4);
            }
            a[0] = a0.x; a[1] = a0.y; a[2] = a0.z; a[3] = a0.w;
            a[4] = a1.x; a[5] = a1.y; a[6] = a1.z; a[7] = a1.w;
        } else {
            ushort4 h0 = make_ushort4(0, 0, 0, 0), h1 = make_ushort4(0, 0, 0, 0);
            if (validA) {
                h0 = *(const ushort4*)((const unsigned short*)in + (size_t)nodeA * 64 + kb);
                h1 = *(const ushort4*)((const unsigned short*)in + (size_t)nodeA * 64 + kb + 4);
            }
            a[0] = bf2f(h0.x); a[1] = bf2f(h0.y); a[2] = bf2f(h0.z); a[3] = bf2f(h0.w);
            a[4] = bf2f(h1.x); a[5] = bf2f(h1.y); a[6] = bf2f(h1.z); a[7] = bf2f(h1.w);
        }
        if (RELU) {
#pragma unroll
            for (int i = 0; i < 8; i++) a[i] = fmaxf(a[i] + bias[kb + i], 0.f);
        }
        bf16x8 af;
#pragma unroll
        for (int i = 0; i < 8; i++) af[i] = (short)f2bf(a[i]);

        const bf16x8 b0f = *(const bf16x8*)(Wt + ((0 * 16 + col) * 64 + kb));
        const bf16x8 b1f = *(const bf16x8*)(Wt + ((1 * 16 + col) * 64 + kb));
        const bf16x8 b2f = *(const bf16x8*)(Wt + ((2 * 16 + col) * 64 + kb));
        const bf16x8 b3f = *(const bf16x8*)(Wt + ((3 * 16 + col) * 64 + kb));
        acc0 = __builtin_amdgcn_mfma_f32_16x16x32_bf16(af, b0f, acc0, 0, 0, 0);
        acc1 = __builtin_amdgcn_mfma_f32_16x16x32_bf16(af, b1f, acc1, 0, 0, 0);
        acc2 = __builtin_amdgcn_mfma_f32_16x16x32_bf16(af, b2f, acc2, 0, 0, 0);
        acc3 = __builtin_amdgcn_mfma_f32_16x16x32_bf16(af, b3f, acc3, 0, 0, 0);
    }

#pragma unroll
    for (int r = 0; r < 4; r++) {
        int nn = node0w + quad * 4 + r;
        if (nn < n) {
            size_t base = (size_t)nn * 64 + col;
            out[base +  0] = f2bf(acc0[r]);
            out[base + 16] = f2bf(acc1[r]);
            out[base + 32] = f2bf(acc2[r]);
            out[base + 48] = f2bf(acc3[r]);
        }
    }
}

template<bool RELU, typename AT>
__global__ __launch_bounds__(256)
void k_gemm(const AT* __restrict__ in, const unsigned short* __restrict__ Wt,
            const float* __restrict__ bias, unsigned short* __restrict__ out, int n) {
    gemm_body<RELU, AT>(blockIdx.x, in, Wt, bias, out, n);
}

// ---------------- FUSED: wfill blocks + layer-1 GEMM blocks -------------------
__global__ __launch_bounds__(256)
void k_wfgemm1(const int* __restrict__ csr_s, const float* __restrict__ dinv,
               float* __restrict__ csr_w, int nE, int n, int wfB,
               const float* __restrict__ x, const unsigned short* __restrict__ Wt,
               unsigned short* __restrict__ hW) {
    if (blockIdx.x < wfB) {
        int e = blockIdx.x * 256 + threadIdx.x;
        if (e < nE) {
            int s = csr_s[e];
            s = max(0, min(s, n - 1));
            csr_w[e] = dinv[s];
        }
        return;
    }
    gemm_body<false, float>(blockIdx.x - wfB, x, Wt, nullptr, hW, n);
}

// ---------------- aggregation: FOUR nodes per wave ----------------------------
// Lane quarter q (= lane>>4) stages node q's edges into 16 slots (lane&15).
// Inner loop: wave-uniform shfl indices, full-row 64-lane gathers, 4
// independent chains. Invalid slots contribute w=0 (tail-free).
template<int LAYER>
__global__ __launch_bounds__(256)
void k_agg(const unsigned short* __restrict__ hW, const int* __restrict__ rowptr,
           const int* __restrict__ rowend, const int* __restrict__ csr_s,
           const float* __restrict__ csr_w, const float* __restrict__ dinv,
           unsigned short* __restrict__ aggb, int n, int nE) {
    const int lane = threadIdx.x & 63;
    const int wid  = threadIdx.x >> 6;
    const int q    = lane >> 4;        // which of my wave's 4 nodes I stage for
    const int slot = lane & 15;
    const int node0 = blockIdx.x * 16 + wid * 4;   // wave's first node
    if (node0 >= n) return;

    // Per-node state (uniform across wave via shfl of per-quarter values).
    int   myNode = node0 + q;
    bool  myValid = myNode < n;
    int   myRow = 0, myEnd = 0;
    float myDi = 0.f;
    if (myValid) {
        myRow = rowptr[myNode]; myEnd = rowend[myNode];
        myRow = max(0, min(myRow, nE)); myEnd = max(myRow, min(myEnd, nE));
        myEnd = min(myEnd, myRow + MAXDEG);
        myDi  = dinv[myNode];
    }

    // Self-loop init: 4 accumulator chains (acc[q] lives in all 64 lanes).
    float acc0, acc1, acc2, acc3;
    {
        int   n0 = node0,            n1 = min(node0 + 1, n - 1);
        int   n2 = min(node0 + 2, n - 1), n3 = min(node0 + 3, n - 1);
        float d0 = __shfl(myDi, 0),  d1 = __shfl(myDi, 16);
        float d2 = __shfl(myDi, 32), d3 = __shfl(myDi, 48);
        acc0 = d0 * d0 * bf2f(hW[(size_t)n0 * 64 + lane]);
        acc1 = d1 * d1 * bf2f(hW[(size_t)n1 * 64 + lane]);
        acc2 = d2 * d2 * bf2f(hW[(size_t)n2 * 64 + lane]);
        acc3 = d3 * d3 * bf2f(hW[(size_t)n3 * 64 + lane]);
    }

    int myBase = myRow;
    while (__any(myBase < myEnd)) {
        int myM = max(0, min(16, myEnd - myBase));   // my node's staged count
        int   s_l = 0;
        float w_l = 0.f;
        if (slot < myM) {
            int e = myBase + slot;
            s_l = csr_s[e];
            w_l = csr_w[e] * myDi;
        }
        // wave-max staged count
        int m = myM;
        m = max(m, __shfl_xor(m, 16));
        m = max(m, __shfl_xor(m, 32));

        int j = 0;
        for (; j + 2 <= m; j += 2) {
            int   s00 = __shfl(s_l, j),      s01 = __shfl(s_l, j + 1);
            int   s10 = __shfl(s_l, j + 16), s11 = __shfl(s_l, j + 17);
            int   s20 = __shfl(s_l, j + 32), s21 = __shfl(s_l, j + 33);
            int   s30 = __shfl(s_l, j + 48), s31 = __shfl(s_l, j + 49);
            float w00 = __shfl(w_l, j),      w01 = __shfl(w_l, j + 1);
            float w10 = __shfl(w_l, j + 16), w11 = __shfl(w_l, j + 17);
            float w20 = __shfl(w_l, j + 32), w21 = __shfl(w_l, j + 33);
            float w30 = __shfl(w_l, j + 48), w31 = __shfl(w_l, j + 49);
            float h00 = bf2f(hW[(size_t)s00 * 64 + lane]);
            float h01 = bf2f(hW[(size_t)s01 * 64 + lane]);
            float h10 = bf2f(hW[(size_t)s10 * 64 + lane]);
            float h11 = bf2f(hW[(size_t)s11 * 64 + lane]);
            float h20 = bf2f(hW[(size_t)s20 * 64 + lane]);
            float h21 = bf2f(hW[(size_t)s21 * 64 + lane]);
            float h30 = bf2f(hW[(size_t)s30 * 64 + lane]);
            float h31 = bf2f(hW[(size_t)s31 * 64 + lane]);
            acc0 += w00 * h00 + w01 * h01;
            acc1 += w10 * h10 + w11 * h11;
            acc2 += w20 * h20 + w21 * h21;
            acc3 += w30 * h30 + w31 * h31;
        }
        for (; j < m; j++) {
            int   s0 = __shfl(s_l, j);
            int   s1 = __shfl(s_l, j + 16);
            int   s2 = __shfl(s_l, j + 32);
            int   s3 = __shfl(s_l, j + 48);
            float w0 = __shfl(w_l, j);
            float w1 = __shfl(w_l, j + 16);
            float w2 = __shfl(w_l, j + 32);
            float w3 = __shfl(w_l, j + 48);
            acc0 += w0 * bf2f(hW[(size_t)s0 * 64 + lane]);
            acc1 += w1 * bf2f(hW[(size_t)s1 * 64 + lane]);
            acc2 += w2 * bf2f(hW[(size_t)s2 * 64 + lane]);
            acc3 += w3 * bf2f(hW[(size_t)s3 * 64 + lane]);
        }
        myBase += myM;
    }

    if (node0 + 0 < n) aggb[(size_t)(node0 + 0) * 64 + lane] = f2bf(acc0);
    if (node0 + 1 < n) aggb[(size_t)(node0 + 1) * 64 + lane] = f2bf(acc1);
    if (node0 + 2 < n) aggb[(size_t)(node0 + 2) * 64 + lane] = f2bf(acc2);
    if (node0 + 3 < n) aggb[(size_t)(node0 + 3) * 64 + lane] = f2bf(acc3);
}

// ---------------- pooling (run-length pre-reduce; few atomics) ----------------
__global__ void k_pool(const unsigned short* __restrict__ aggb,
                       const int* __restrict__ batch,
                       float* __restrict__ pool, float* __restrict__ cnt, int n) {
    const int lane = threadIdx.x;       // 64 threads
    const int base = blockIdx.x * 64;
    int g_cur = -1, run = 0;
    float acc = 0.f;
    for (int j = 0; j < 64; j++) {
        int node = base + j;
        if (node >= n) break;
        int g = batch[node];
        if (g != g_cur) {
            if (g_cur >= 0) {
                atomAddF(&pool[g_cur * 64 + lane], acc);
                if (lane == 0) atomAddF(&cnt[g_cur], (float)run);
            }
            g_cur = g; acc = 0.f; run = 0;
        }
        acc += bf2f(aggb[(size_t)node * 64 + lane]);
        run++;
    }
    if (g_cur >= 0) {
        atomAddF(&pool[g_cur * 64 + lane], acc);
        if (lane == 0) atomAddF(&cnt[g_cur], (float)run);
    }
}

// ---------------- classifier ----------------
__global__ void k_final(const float* __restrict__ pool, const float* __restrict__ cnt,
                        const float* __restrict__ b3, const float* __restrict__ Wl,
                        const float* __restrict__ bl, float* __restrict__ out) {
    __shared__ float s[64];
    const int g = blockIdx.x, t = threadIdx.x;
    float c = fmaxf(cnt[g], 1.0f);
    s[t] = pool[g * 64 + t] / c + b3[t];
    __syncthreads();
    if (t < 10) {
        float acc = bl[t];
#pragma unroll
        for (int k = 0; k < 64; k++) acc += s[k] * Wl[k * 10 + t];
        out[g * 10 + t] = acc;
    }
}

extern "C" void kernel_launch(void* const* d_in, const int* in_sizes, int n_in,
                              void* d_out, int out_size, void* d_ws, size_t ws_size,
                              hipStream_t stream) {
    const float* x   = (const float*)d_in[0];
    const int*   ei  = (const int*)d_in[1];
    const int*   bat = (const int*)d_in[2];
    const float* W1  = (const float*)d_in[3];
    const float* b1  = (const float*)d_in[4];
    const float* W2  = (const float*)d_in[5];
    const float* b2  = (const float*)d_in[6];
    const float* W3  = (const float*)d_in[7];
    const float* b3  = (const float*)d_in[8];
    const float* Wl  = (const float*)d_in[9];
    const float* bl  = (const float*)d_in[10];
    float* out = (float*)d_out;

    const int N_ = in_sizes[0] / 64;
    const int E_ = in_sizes[1] / 2;
    const int G_ = out_size / 10;
    const int NB_ = (N_ + BNODES - 1) >> BSHIFT;
    const int bin_blocks = (E_ + EPB - 1) / EPB;

    // workspace layout
    char* p = (char*)d_ws;
    int*   staging = (int*)p;   p += (size_t)E_ * 4;
    int*   csr_s  = (int*)p;    p += (size_t)E_ * 4;
    float* csr_w  = (float*)p;  p += (size_t)E_ * 4;
    unsigned short* aggb = (unsigned short*)p; p += (size_t)N_ * 64 * 2;
    unsigned short* hW   = (unsigned short*)p; p += (size_t)N_ * 64 * 2;
    float* dinv   = (float*)p;  p += (size_t)N_ * 4;
    int*   rowptr = (int*)p;    p += (size_t)N_ * 4;
    int*   rowend = (int*)p;    p += (size_t)N_ * 4;
    float* pool   = (float*)p;  p += (size_t)G_ * 64 * 4;
    float* cnt    = (float*)p;  p += (size_t)G_ * 4;
    unsigned short* Wt = (unsigned short*)p; p += 3 * 4096 * 2;
    int*   bcnt   = (int*)p;    p += (size_t)(NB_ + 1) * 4;
    int*   bbase  = (int*)p;    p += (size_t)(NB_ + 1) * 4;
    int*   cnt_all = (int*)p;   p += (size_t)bin_blocks * NB_ * 4;

    const int* srcp = ei;
    const int* dstp = ei + E_;

    // pool + cnt zeroed by k_bhist's extra block (they are contiguous)
    k_bhist<<<bin_blocks + 4, 256, 0, stream>>>(dstp, cnt_all, E_, NB_,
                                                bin_blocks, W1, W2, W3, Wt,
                                                pool, G_ * 64 + G_);
    k_colscan<<<(NB_ + 3) / 4, 256, 0, stream>>>(cnt_all, bcnt, bin_blocks, NB_);
    k_bscan<<<1, 256, 0, stream>>>(bcnt, bbase, NB_, E_);
    k_bucket<<<bin_blocks, 256, 0, stream>>>(srcp, dstp, bbase, cnt_all,
                                             staging, E_, NB_);
    k_sort<<<NB_, 256, 0, stream>>>(staging, bbase, csr_s, rowptr, rowend,
                                    dinv, N_, E_);

    const int gemm_blocks = (N_ + 63) / 64;
    const int agg_blocks  = (N_ + 15) / 16;
    const int wf_blocks   = (E_ + 255) / 256;

    // Fused wfill + Layer-1 GEMM
    k_wfgemm1<<<wf_blocks + gemm_blocks, 256, 0, stream>>>(
        csr_s, dinv, csr_w, E_, N_, wf_blocks, x, Wt, hW);
    k_agg<1><<<agg_blocks, 256, 0, stream>>>(hW, rowptr, rowend, csr_s, csr_w,
                                             dinv, aggb, N_, E_);
    // Layer 2
    k_gemm<true, unsigned short><<<gemm_blocks, 256, 0, stream>>>(aggb, Wt + 4096,
                                                                  b1, hW, N_);
    k_agg<2><<<agg_blocks, 256, 0, stream>>>(hW, rowptr, rowend, csr_s, csr_w,
                                             dinv, aggb, N_, E_);
    // Layer 3
    k_gemm<true, unsigned short><<<gemm_blocks, 256, 0, stream>>>(aggb, Wt + 8192,
                                                                  b2, hW, N_);
    k_agg<3><<<agg_blocks, 256, 0, stream>>>(hW, rowptr, rowend, csr_s, csr_w,
                                             dinv, aggb, N_, E_);

    // Pool (b3 folded into final) + classifier
    k_pool<<<(N_ + 63) / 64, 64, 0, stream>>>(aggb, bat, pool, cnt, N_);
    k_final<<<G_, 64, 0, stream>>>(pool, cnt, b3, Wl, bl, out);
}

// Round 16
// 344.481 us; speedup vs baseline: 1.0186x; 1.0186x over previous
//
#include <hip/hip_runtime.h>
#include <hip/hip_bf16.h>

// GCN on MI355X — FINAL (R14 form, measured best: ~346us).
// Pipeline (13 dispatches):
//   k_bhist   - per-block bucket histogram -> cnt_all (no atomics)
//               + merged wprep (W->bf16 Wt) + pool/cnt zeroing
//   k_colscan - one wave per bucket shfl-scan of cnt_all columns
//   k_bscan   - exclusive scan over buckets -> bbase
//   k_bucket  - placement only (lbase = bbase + cnt_all precomputed)
//   k_sort    - per-bucket LDS counting sort -> CSR + rowptr/rowend/dinv
//   k_wfgemm1 - FUSED: wfill blocks (csr_w[e]=dinv[csr_s[e]]) + GEMM-1 blocks
//   k_agg x3  - TWO nodes per wave (empirical optimum: 1-node=46.6us,
//               2-node=43.0us, 4-node=49.7us); bf16 gathers -> bf16 aggb.
//               Latency/gather-rate bound: ~63G line-req/s, dur invariant
//               to +-75% traffic changes (R7..R11 evidence).
//   k_gemm x2 - MFMA 16x16x32 bf16, bias+relu+cast fused
//   k_pool    - run-length pre-reduce (RULE from R3/R13: never >~100
//               atomics/address; pre-reduce first)
//   k_final
// All ws-derived loop bounds are clamped (rocprof counter-replay safety).

#define BSHIFT 7
#define BNODES (1 << BSHIFT)
#define EPB    8192
#define MAXDEG 8192
#define MAXBUCKET 32768

typedef __attribute__((ext_vector_type(8))) short bf16x8;
typedef __attribute__((ext_vector_type(4))) float f32x4;

__device__ __forceinline__ void atomAddF(float* p, float v) {
#if defined(__gfx90a__) || defined(__gfx940__) || defined(__gfx941__) || defined(__gfx942__) || defined(__gfx950__)
    unsafeAtomicAdd(p, v);
#else
    atomicAdd(p, v);
#endif
}

__device__ __forceinline__ unsigned short f2bf(float x) {   // RNE fp32->bf16
    unsigned u = __float_as_uint(x);
    u += 0x7FFFu + ((u >> 16) & 1u);
    return (unsigned short)(u >> 16);
}
__device__ __forceinline__ float bf2f(unsigned short b) {
    return __uint_as_float((unsigned)b << 16);
}

// ---------------- histogram + weight prep + pool zeroing ----------------
__global__ __launch_bounds__(256)
void k_bhist(const int* __restrict__ dst, int* __restrict__ cnt_all,
             int nE, int nBuckets, int binBlocks,
             const float* __restrict__ W1, const float* __restrict__ W2,
             const float* __restrict__ W3, unsigned short* __restrict__ Wt,
             float* __restrict__ pool, int poolN) {
    if (blockIdx.x >= binBlocks) {
        int li = blockIdx.x - binBlocks;          // 0..2 wprep, 3 = pool zero
        if (li < 3) {
            const float* W = (li == 0) ? W1 : ((li == 1) ? W2 : W3);
            unsigned short* o = Wt + li * 4096;
            for (int idx = threadIdx.x; idx < 4096; idx += 256) {
                int h = idx >> 6, k = idx & 63;
                o[idx] = f2bf(W[k * 64 + h]);
            }
        } else {
            for (int i = threadIdx.x; i < poolN; i += 256) pool[i] = 0.f;
        }
        return;
    }
    __shared__ int cnt[1024];
    const int t = threadIdx.x;
    const int blk = blockIdx.x * EPB;
    for (int b = t; b < nBuckets; b += 256) cnt[b] = 0;
    __syncthreads();
#pragma unroll 4
    for (int i = 0; i < EPB / 256; i++) {
        int e = blk + i * 256 + t;
        if (e < nE) atomicAdd(&cnt[dst[e] >> BSHIFT], 1);
    }
    __syncthreads();
    for (int b = t; b < nBuckets; b += 256)
        cnt_all[(size_t)blockIdx.x * nBuckets + b] = cnt[b];
}

// ---------------- column scan: one wave per bucket ----------------
__global__ __launch_bounds__(256)
void k_colscan(int* __restrict__ cnt_all, int* __restrict__ bcnt,
               int nBlocks, int nBuckets) {
    const int lane = threadIdx.x & 63;
    const int b = blockIdx.x * 4 + (threadIdx.x >> 6);
    if (b >= nBuckets) return;
    int running = 0;
    for (int c = 0; c < nBlocks; c += 64) {
        int blk = c + lane;
        int v = (blk < nBlocks) ? cnt_all[(size_t)blk * nBuckets + b] : 0;
        int incl = v;
#pragma unroll
        for (int off = 1; off < 64; off <<= 1) {
            int tv = __shfl_up(incl, off);
            if (lane >= off) incl += tv;
        }
        if (blk < nBlocks) cnt_all[(size_t)blk * nBuckets + b] = running + (incl - v);
        running += __shfl(incl, 63);
    }
    if (lane == 0) bcnt[b] = running;
}

// ---------------- bucket scan (nb <= 1024) -> bbase ----------------
__global__ void k_bscan(const int* __restrict__ bcnt, int* __restrict__ bbase,
                        int nb, int nE) {
    __shared__ int s[256];
    const int t = threadIdx.x;
    const int base = t * 4;
    int v0 = (base + 0 < nb) ? bcnt[base + 0] : 0;
    int v1 = (base + 1 < nb) ? bcnt[base + 1] : 0;
    int v2 = (base + 2 < nb) ? bcnt[base + 2] : 0;
    int v3 = (base + 3 < nb) ? bcnt[base + 3] : 0;
    int tsum = v0 + v1 + v2 + v3;
    s[t] = tsum;
    __syncthreads();
    for (int off = 1; off < 256; off <<= 1) {
        int val = 0;
        if (t >= off) val = s[t - off];
        __syncthreads();
        if (t >= off) s[t] += val;
        __syncthreads();
    }
    int excl = s[t] - tsum;
    if (base + 0 < nb) bbase[base + 0] = excl;
    if (base + 1 < nb) bbase[base + 1] = excl + v0;
    if (base + 2 < nb) bbase[base + 2] = excl + v0 + v1;
    if (base + 3 < nb) bbase[base + 3] = excl + v0 + v1 + v2;
    if (t == 0) bbase[nb] = nE;
}

// ---------------- bucket placement ----------------
__global__ __launch_bounds__(256)
void k_bucket(const int* __restrict__ src, const int* __restrict__ dst,
              const int* __restrict__ bbase, const int* __restrict__ cnt_all,
              int* __restrict__ staging, int nE, int nBuckets) {
    __shared__ int cnt[1024];
    __shared__ int lbase[1024];
    const int t = threadIdx.x;
    const int blk = blockIdx.x * EPB;

    for (int b = t; b < nBuckets; b += 256) {
        lbase[b] = bbase[b] + cnt_all[(size_t)blockIdx.x * nBuckets + b];
        cnt[b] = 0;
    }
    __syncthreads();
#pragma unroll 4
    for (int i = 0; i < EPB / 256; i++) {
        int e = blk + i * 256 + t;
        if (e < nE) {
            int s0 = src[e], d0 = dst[e];
            int b = d0 >> BSHIFT;
            int off = atomicAdd(&cnt[b], 1);
            int pos = lbase[b] + off;
            if ((unsigned)pos < (unsigned)nE)
                staging[pos] = (s0 << BSHIFT) | (d0 & (BNODES - 1));
        }
    }
}

// ---------------- per-bucket counting sort -> CSR + rowptr/rowend/dinv ----------
__global__ __launch_bounds__(256)
void k_sort(const int* __restrict__ staging, const int* __restrict__ bbase,
            int* __restrict__ csr_s, int* __restrict__ rowptr,
            int* __restrict__ rowend, float* __restrict__ dinv,
            int n, int nE) {
    __shared__ int c[BNODES];
    __shared__ int sc[BNODES];
    __shared__ int cur[BNODES];
    const int t = threadIdx.x;
    const int b = blockIdx.x;
    const int node0 = b << BSHIFT;

    int seg0 = bbase[b];
    int seg1 = bbase[b + 1];
    seg0 = max(0, min(seg0, nE));
    seg1 = max(seg0, min(seg1, nE));
    seg1 = min(seg1, seg0 + MAXBUCKET);

    if (t < BNODES) c[t] = 0;
    __syncthreads();
    for (int e = seg0 + t; e < seg1; e += 256)
        atomicAdd(&c[staging[e] & (BNODES - 1)], 1);
    __syncthreads();
    if (t < BNODES) sc[t] = c[t];
    __syncthreads();
    for (int off = 1; off < BNODES; off <<= 1) {
        int v = 0;
        if (t >= off && t < BNODES) v = sc[t - off];
        __syncthreads();
        if (t >= off && t < BNODES) sc[t] += v;
        __syncthreads();
    }
    if (t < BNODES) {
        int excl = sc[t] - c[t];
        cur[t] = excl;
        int node = node0 + t;
        if (node < n) {
            rowptr[node] = seg0 + excl;
            rowend[node] = seg0 + excl + c[t];
            dinv[node]   = rsqrtf((float)c[t] + 1.0f);
        }
    }
    __syncthreads();
    for (int e = seg0 + t; e < seg1; e += 256) {
        int p = staging[e];
        int l = p & (BNODES - 1);
        int pos = seg0 + atomicAdd(&cur[l], 1);
        if ((unsigned)pos < (unsigned)nE)
            csr_s[pos] = ((unsigned)p) >> BSHIFT;
    }
}

// ---------------- MFMA GEMM body (shared by k_gemm and k_wfgemm1) -------------
template<bool RELU, typename AT>
__device__ __forceinline__
void gemm_body(int bid, const AT* __restrict__ in,
               const unsigned short* __restrict__ Wt,
               const float* __restrict__ bias,
               unsigned short* __restrict__ out, int n) {
    const int lane = threadIdx.x & 63;
    const int wid  = threadIdx.x >> 6;
    const int col  = lane & 15;
    const int quad = lane >> 4;
    const int node0w = bid * 64 + wid * 16;
    const int nodeA  = node0w + col;
    const bool validA = nodeA < n;

    f32x4 zero4 = {0.f, 0.f, 0.f, 0.f};
    f32x4 acc0 = zero4, acc1 = zero4, acc2 = zero4, acc3 = zero4;

#pragma unroll
    for (int ks = 0; ks < 64; ks += 32) {
        const int kb = ks + quad * 8;
        float a[8];
        if constexpr (sizeof(AT) == 4) {
            float4 a0 = make_float4(0.f, 0.f, 0.f, 0.f);
            float4 a1 = make_float4(0.f, 0.f, 0.f, 0.f);
            if (validA) {
                a0 = *(const float4*)((const float*)in + (size_t)nodeA * 64 + kb);
                a1 = *(const float4*)((const float*)in + (size_t)nodeA * 64 + kb + 4);
            }
            a[0] = a0.x; a[1] = a0.y; a[2] = a0.z; a[3] = a0.w;
            a[4] = a1.x; a[5] = a1.y; a[6] = a1.z; a[7] = a1.w;
        } else {
            ushort4 h0 = make_ushort4(0, 0, 0, 0), h1 = make_ushort4(0, 0, 0, 0);
            if (validA) {
                h0 = *(const ushort4*)((const unsigned short*)in + (size_t)nodeA * 64 + kb);
                h1 = *(const ushort4*)((const unsigned short*)in + (size_t)nodeA * 64 + kb + 4);
            }
            a[0] = bf2f(h0.x); a[1] = bf2f(h0.y); a[2] = bf2f(h0.z); a[3] = bf2f(h0.w);
            a[4] = bf2f(h1.x); a[5] = bf2f(h1.y); a[6] = bf2f(h1.z); a[7] = bf2f(h1.w);
        }
        if (RELU) {
#pragma unroll
            for (int i = 0; i < 8; i++) a[i] = fmaxf(a[i] + bias[kb + i], 0.f);
        }
        bf16x8 af;
#pragma unroll
        for (int i = 0; i < 8; i++) af[i] = (short)f2bf(a[i]);

        const bf16x8 b0f = *(const bf16x8*)(Wt + ((0 * 16 + col) * 64 + kb));
        const bf16x8 b1f = *(const bf16x8*)(Wt + ((1 * 16 + col) * 64 + kb));
        const bf16x8 b2f = *(const bf16x8*)(Wt + ((2 * 16 + col) * 64 + kb));
        const bf16x8 b3f = *(const bf16x8*)(Wt + ((3 * 16 + col) * 64 + kb));
        acc0 = __builtin_amdgcn_mfma_f32_16x16x32_bf16(af, b0f, acc0, 0, 0, 0);
        acc1 = __builtin_amdgcn_mfma_f32_16x16x32_bf16(af, b1f, acc1, 0, 0, 0);
        acc2 = __builtin_amdgcn_mfma_f32_16x16x32_bf16(af, b2f, acc2, 0, 0, 0);
        acc3 = __builtin_amdgcn_mfma_f32_16x16x32_bf16(af, b3f, acc3, 0, 0, 0);
    }

#pragma unroll
    for (int r = 0; r < 4; r++) {
        int nn = node0w + quad * 4 + r;
        if (nn < n) {
            size_t base = (size_t)nn * 64 + col;
            out[base +  0] = f2bf(acc0[r]);
            out[base + 16] = f2bf(acc1[r]);
            out[base + 32] = f2bf(acc2[r]);
            out[base + 48] = f2bf(acc3[r]);
        }
    }
}

template<bool RELU, typename AT>
__global__ __launch_bounds__(256)
void k_gemm(const AT* __restrict__ in, const unsigned short* __restrict__ Wt,
            const float* __restrict__ bias, unsigned short* __restrict__ out, int n) {
    gemm_body<RELU, AT>(blockIdx.x, in, Wt, bias, out, n);
}

// ---------------- FUSED: wfill blocks + layer-1 GEMM blocks -------------------
__global__ __launch_bounds__(256)
void k_wfgemm1(const int* __restrict__ csr_s, const float* __restrict__ dinv,
               float* __restrict__ csr_w, int nE, int n, int wfB,
               const float* __restrict__ x, const unsigned short* __restrict__ Wt,
               unsigned short* __restrict__ hW) {
    if (blockIdx.x < wfB) {
        int e = blockIdx.x * 256 + threadIdx.x;
        if (e < nE) {
            int s = csr_s[e];
            s = max(0, min(s, n - 1));
            csr_w[e] = dinv[s];
        }
        return;
    }
    gemm_body<false, float>(blockIdx.x - wfB, x, Wt, nullptr, hW, n);
}

// ---------------- aggregation: two nodes per wave (empirical optimum) ---------
template<int LAYER>
__global__ __launch_bounds__(256)
void k_agg(const unsigned short* __restrict__ hW, const int* __restrict__ rowptr,
           const int* __restrict__ rowend, const int* __restrict__ csr_s,
           const float* __restrict__ csr_w, const float* __restrict__ dinv,
           unsigned short* __restrict__ aggb, int n, int nE) {
    const int lane = threadIdx.x & 63;
    const int wid  = threadIdx.x >> 6;
    const int nA = blockIdx.x * 8 + wid * 2;
    const int nB = nA + 1;
    if (nA >= n) return;
    const bool vB = (nB < n);

    int rowA = rowptr[nA], endA = rowend[nA];
    rowA = max(0, min(rowA, nE)); endA = max(rowA, min(endA, nE));
    endA = min(endA, rowA + MAXDEG);
    int rowB = 0, endB = 0;
    if (vB) {
        rowB = rowptr[nB]; endB = rowend[nB];
        rowB = max(0, min(rowB, nE)); endB = max(rowB, min(endB, nE));
        endB = min(endB, rowB + MAXDEG);
    }
    const float diA = dinv[nA];
    const float diB = vB ? dinv[nB] : 0.f;

    float a0 = diA * diA * bf2f(hW[(size_t)nA * 64 + lane]);
    float a1 = 0.f, a2 = 0.f, a3 = 0.f;
    float b0 = vB ? diB * diB * bf2f(hW[(size_t)nB * 64 + lane]) : 0.f;
    float b1 = 0.f, b2 = 0.f, b3 = 0.f;

    int baseA = rowA, baseB = rowB;
    while (baseA < endA || baseB < endB) {
        int mA = max(0, min(32, endA - baseA));
        int mB = max(0, min(32, endB - baseB));
        int   s_l = 0;
        float w_l = 0.f;
        if (lane < 32) {
            if (lane < mA) {
                int e = baseA + lane;
                s_l = csr_s[e];
                w_l = csr_w[e] * diA;
            }
        } else {
            int l2 = lane - 32;
            if (l2 < mB) {
                int e = baseB + l2;
                s_l = csr_s[e];
                w_l = csr_w[e] * diB;
            }
        }
        const int m = max(mA, mB);
        int j = 0;
        for (; j + 4 <= m; j += 4) {
            int   sA0 = __shfl(s_l, j),      sA1 = __shfl(s_l, j + 1);
            int   sA2 = __shfl(s_l, j + 2),  sA3 = __shfl(s_l, j + 3);
            int   sB0 = __shfl(s_l, j + 32), sB1 = __shfl(s_l, j + 33);
            int   sB2 = __shfl(s_l, j + 34), sB3 = __shfl(s_l, j + 35);
            float wA0 = __shfl(w_l, j),      wA1 = __shfl(w_l, j + 1);
            float wA2 = __shfl(w_l, j + 2),  wA3 = __shfl(w_l, j + 3);
            float wB0 = __shfl(w_l, j + 32), wB1 = __shfl(w_l, j + 33);
            float wB2 = __shfl(w_l, j + 34), wB3 = __shfl(w_l, j + 35);
            float hA0 = bf2f(hW[(size_t)sA0 * 64 + lane]);
            float hA1 = bf2f(hW[(size_t)sA1 * 64 + lane]);
            float hA2 = bf2f(hW[(size_t)sA2 * 64 + lane]);
            float hA3 = bf2f(hW[(size_t)sA3 * 64 + lane]);
            float hB0 = bf2f(hW[(size_t)sB0 * 64 + lane]);
            float hB1 = bf2f(hW[(size_t)sB1 * 64 + lane]);
            float hB2 = bf2f(hW[(size_t)sB2 * 64 + lane]);
            float hB3 = bf2f(hW[(size_t)sB3 * 64 + lane]);
            a0 += wA0 * hA0; a1 += wA1 * hA1;
            a2 += wA2 * hA2; a3 += wA3 * hA3;
            b0 += wB0 * hB0; b1 += wB1 * hB1;
            b2 += wB2 * hB2; b3 += wB3 * hB3;
        }
        for (; j < m; j++) {
            int   sA = __shfl(s_l, j);
            float wA = __shfl(w_l, j);
            int   sB = __shfl(s_l, j + 32);
            float wB = __shfl(w_l, j + 32);
            a0 += wA * bf2f(hW[(size_t)sA * 64 + lane]);
            b0 += wB * bf2f(hW[(size_t)sB * 64 + lane]);
        }
        baseA += mA;
        baseB += mB;
    }
    aggb[(size_t)nA * 64 + lane] = f2bf((a0 + a1) + (a2 + a3));
    if (vB) aggb[(size_t)nB * 64 + lane] = f2bf((b0 + b1) + (b2 + b3));
}

// ---------------- pooling (run-length pre-reduce; few atomics) ----------------
__global__ void k_pool(const unsigned short* __restrict__ aggb,
                       const int* __restrict__ batch,
                       float* __restrict__ pool, float* __restrict__ cnt, int n) {
    const int lane = threadIdx.x;       // 64 threads
    const int base = blockIdx.x * 64;
    int g_cur = -1, run = 0;
    float acc = 0.f;
    for (int j = 0; j < 64; j++) {
        int node = base + j;
        if (node >= n) break;
        int g = batch[node];
        if (g != g_cur) {
            if (g_cur >= 0) {
                atomAddF(&pool[g_cur * 64 + lane], acc);
                if (lane == 0) atomAddF(&cnt[g_cur], (float)run);
            }
            g_cur = g; acc = 0.f; run = 0;
        }
        acc += bf2f(aggb[(size_t)node * 64 + lane]);
        run++;
    }
    if (g_cur >= 0) {
        atomAddF(&pool[g_cur * 64 + lane], acc);
        if (lane == 0) atomAddF(&cnt[g_cur], (float)run);
    }
}

// ---------------- classifier ----------------
__global__ void k_final(const float* __restrict__ pool, const float* __restrict__ cnt,
                        const float* __restrict__ b3, const float* __restrict__ Wl,
                        const float* __restrict__ bl, float* __restrict__ out) {
    __shared__ float s[64];
    const int g = blockIdx.x, t = threadIdx.x;
    float c = fmaxf(cnt[g], 1.0f);
    s[t] = pool[g * 64 + t] / c + b3[t];
    __syncthreads();
    if (t < 10) {
        float acc = bl[t];
#pragma unroll
        for (int k = 0; k < 64; k++) acc += s[k] * Wl[k * 10 + t];
        out[g * 10 + t] = acc;
    }
}

extern "C" void kernel_launch(void* const* d_in, const int* in_sizes, int n_in,
                              void* d_out, int out_size, void* d_ws, size_t ws_size,
                              hipStream_t stream) {
    const float* x   = (const float*)d_in[0];
    const int*   ei  = (const int*)d_in[1];
    const int*   bat = (const int*)d_in[2];
    const float* W1  = (const float*)d_in[3];
    const float* b1  = (const float*)d_in[4];
    const float* W2  = (const float*)d_in[5];
    const float* b2  = (const float*)d_in[6];
    const float* W3  = (const float*)d_in[7];
    const float* b3  = (const float*)d_in[8];
    const float* Wl  = (const float*)d_in[9];
    const float* bl  = (const float*)d_in[10];
    float* out = (float*)d_out;

    const int N_ = in_sizes[0] / 64;
    const int E_ = in_sizes[1] / 2;
    const int G_ = out_size / 10;
    const int NB_ = (N_ + BNODES - 1) >> BSHIFT;
    const int bin_blocks = (E_ + EPB - 1) / EPB;

    // workspace layout
    char* p = (char*)d_ws;
    int*   staging = (int*)p;   p += (size_t)E_ * 4;
    int*   csr_s  = (int*)p;    p += (size_t)E_ * 4;
    float* csr_w  = (float*)p;  p += (size_t)E_ * 4;
    unsigned short* aggb = (unsigned short*)p; p += (size_t)N_ * 64 * 2;
    unsigned short* hW   = (unsigned short*)p; p += (size_t)N_ * 64 * 2;
    float* dinv   = (float*)p;  p += (size_t)N_ * 4;
    int*   rowptr = (int*)p;    p += (size_t)N_ * 4;
    int*   rowend = (int*)p;    p += (size_t)N_ * 4;
    float* pool   = (float*)p;  p += (size_t)G_ * 64 * 4;
    float* cnt    = (float*)p;  p += (size_t)G_ * 4;
    unsigned short* Wt = (unsigned short*)p; p += 3 * 4096 * 2;
    int*   bcnt   = (int*)p;    p += (size_t)(NB_ + 1) * 4;
    int*   bbase  = (int*)p;    p += (size_t)(NB_ + 1) * 4;
    int*   cnt_all = (int*)p;   p += (size_t)bin_blocks * NB_ * 4;

    const int* srcp = ei;
    const int* dstp = ei + E_;

    // pool + cnt zeroed by k_bhist's extra block (they are contiguous)
    k_bhist<<<bin_blocks + 4, 256, 0, stream>>>(dstp, cnt_all, E_, NB_,
                                                bin_blocks, W1, W2, W3, Wt,
                                                pool, G_ * 64 + G_);
    k_colscan<<<(NB_ + 3) / 4, 256, 0, stream>>>(cnt_all, bcnt, bin_blocks, NB_);
    k_bscan<<<1, 256, 0, stream>>>(bcnt, bbase, NB_, E_);
    k_bucket<<<bin_blocks, 256, 0, stream>>>(srcp, dstp, bbase, cnt_all,
                                             staging, E_, NB_);
    k_sort<<<NB_, 256, 0, stream>>>(staging, bbase, csr_s, rowptr, rowend,
                                    dinv, N_, E_);

    const int gemm_blocks = (N_ + 63) / 64;
    const int agg_blocks  = (N_ + 7) / 8;
    const int wf_blocks   = (E_ + 255) / 256;

    // Fused wfill + Layer-1 GEMM
    k_wfgemm1<<<wf_blocks + gemm_blocks, 256, 0, stream>>>(
        csr_s, dinv, csr_w, E_, N_, wf_blocks, x, Wt, hW);
    k_agg<1><<<agg_blocks, 256, 0, stream>>>(hW, rowptr, rowend, csr_s, csr_w,
                                             dinv, aggb, N_, E_);
    // Layer 2
    k_gemm<true, unsigned short><<<gemm_blocks, 256, 0, stream>>>(aggb, Wt + 4096,
                                                                  b1, hW, N_);
    k_agg<2><<<agg_blocks, 256, 0, stream>>>(hW, rowptr, rowend, csr_s, csr_w,
                                             dinv, aggb, N_, E_);
    // Layer 3
    k_gemm<true, unsigned short><<<gemm_blocks, 256, 0, stream>>>(aggb, Wt + 8192,
                                                                  b2, hW, N_);
    k_agg<3><<<agg_blocks, 256, 0, stream>>>(hW, rowptr, rowend, csr_s, csr_w,
                                             dinv, aggb, N_, E_);

    // Pool (b3 folded into final) + classifier
    k_pool<<<(N_ + 63) / 64, 64, 0, stream>>>(aggb, bat, pool, cnt, N_);
    k_final<<<G_, 64, 0, stream>>>(pool, cnt, b3, Wl, bl, out);
}